// Round 2
// baseline (2397.170 us; speedup 1.0000x reference)
//
#include <hip/hip_runtime.h>
#include <cstdint>
#include <cstddef>

#define BB 8
#define SS 1024
#define EE 512
#define NQB 16
#define FF 2048

typedef unsigned short u16;

__device__ __forceinline__ float u2f(u16 u){ return __uint_as_float(((unsigned)u)<<16); }
__device__ __forceinline__ u16 f2bf(float x){
  unsigned u = __float_as_uint(x);
  u += 0x7FFF + ((u>>16)&1);   // RNE
  return (u16)(u>>16);
}

// dual-dtype global load/store helpers. f=1: fp32 data, f=0: bf16 data.
__device__ __forceinline__ float ldg(const void* p,int f,size_t i){
  return f ? ((const float*)p)[i] : u2f(((const u16*)p)[i]);
}
__device__ __forceinline__ float4 ldg4(const void* p,int f,size_t i){ // i multiple of 4
  float4 r;
  if (f){ r = ((const float4*)p)[i>>2]; }
  else { ushort4 v = ((const ushort4*)p)[i>>2];
         r.x=u2f(v.x); r.y=u2f(v.y); r.z=u2f(v.z); r.w=u2f(v.w); }
  return r;
}
// h accessors: f=1 -> fp32 in d_out; f=0 && bw=1 -> fp32 in ws; else bf16 in d_out.
__device__ __forceinline__ float ldh(const void* ho,const float* hw,int f,int bw,size_t i){
  if (f)  return ((const float*)ho)[i];
  if (bw) return hw[i];
  return u2f(((const u16*)ho)[i]);
}
__device__ __forceinline__ float4 ldh4(const void* ho,const float* hw,int f,int bw,size_t i){
  if (f)  return ((const float4*)ho)[i>>2];
  if (bw) return ((const float4*)hw)[i>>2];
  ushort4 v = ((const ushort4*)ho)[i>>2];
  float4 r; r.x=u2f(v.x); r.y=u2f(v.y); r.z=u2f(v.z); r.w=u2f(v.w); return r;
}
__device__ __forceinline__ void sth(void* ho,float* hw,int f,int bw,size_t i,float v){
  if (f){ ((float*)ho)[i]=v; return; }
  if (bw){ hw[i]=v; return; }
  ((u16*)ho)[i]=f2bf(v);
}
__device__ __forceinline__ void sth4(void* ho,float* hw,int f,int bw,size_t i,float4 v){
  if (f){ ((float4*)ho)[i>>2]=v; return; }
  if (bw){ ((float4*)hw)[i>>2]=v; return; }
  ushort4 o; o.x=f2bf(v.x); o.y=f2bf(v.y); o.z=f2bf(v.z); o.w=f2bf(v.w);
  ((ushort4*)ho)[i>>2]=o;
}

// dtype detector: fp32 data read as u16 pairs has garbage exponents in the
// even (low-half) u16s; bf16 N(0,1) data never has exponent >= 160 (|v|>=2^33).
__global__ void detect_k(const u16* __restrict__ x, int* __restrict__ flag){
  __shared__ int cnt;
  if (threadIdx.x==0) cnt=0;
  __syncthreads();
  int c=0;
  for (int i=threadIdx.x;i<4096;i+=256){
    u16 v = x[(size_t)i*2];
    int ex = (v>>7)&0xFF;
    c += (ex>=160) ? 1 : 0;
  }
  atomicAdd(&cnt,c);
  __syncthreads();
  if (threadIdx.x==0) *flag = (cnt>64) ? 1 : 0;
}

// h = x + pe
__global__ __launch_bounds__(256) void add_pe_k(const void* __restrict__ x,
    const void* __restrict__ pe, void* ho, float* hw,
    const int* __restrict__ flag, int bw){
  int f=*flag;
  size_t e = ((size_t)blockIdx.x*256 + threadIdx.x)*4;
  float4 xv = ldg4(x,f,e);
  float4 pv = ldg4(pe,f,e & (size_t)(SS*EE-1));
  float4 o; o.x=xv.x+pv.x; o.y=xv.y+pv.y; o.z=xv.z+pv.z; o.w=xv.w+pv.w;
  sth4(ho,hw,f,bw,e,o);
}

// attention per (b,head): dk=2, |score|<=sqrt(2) -> single-pass plain-exp softmax
__global__ __launch_bounds__(256) void attn_k(const void* __restrict__ ho,
    const float* __restrict__ hw, const void* __restrict__ theta,
    float* __restrict__ attn, const int* __restrict__ flag, int bw, int l){
  __shared__ float q0[SS], q1[SS];
  int f=*flag;
  int b = blockIdx.x>>3, hd = blockIdx.x&7;
  float c0 = __cosf(ldg(theta,f,(size_t)l*16 + hd*2));
  float c1 = __cosf(ldg(theta,f,(size_t)l*16 + hd*2+1));
  size_t hb = (size_t)b*SS*EE + hd*2;
  for (int j=threadIdx.x; j<SS; j+=256){
    q0[j] = c0*__cosf(ldh(ho,hw,f,bw, hb + (size_t)j*EE));
    q1[j] = c1*__cosf(ldh(ho,hw,f,bw, hb + (size_t)j*EE + 1));
  }
  __syncthreads();
  int r = blockIdx.y*256 + threadIdx.x;
  float a0=q0[r], a1=q1[r], den=0.f, n0=0.f, n1=0.f;
  const float sc = 0.70710678118f;   // 1/sqrt(dk)
  for (int j=0;j<SS;++j){
    float u0=q0[j], u1=q1[j];
    float e = __expf((a0*u0 + a1*u1)*sc);
    den += e; n0 = fmaf(e,u0,n0); n1 = fmaf(e,u1,n1);
  }
  float inv = 1.f/den;
  float* ap = attn + ((size_t)(b*SS + r))*NQB + hd*2;
  ap[0]=n0*inv; ap[1]=n1*inv;
}

// attn @ Wc^T + residual + LayerNorm. One block per token.
__global__ __launch_bounds__(256) void combine_ln_k(void* ho, float* hw,
    const float* __restrict__ attn, const void* __restrict__ Wc,
    const void* __restrict__ g, const void* __restrict__ bb,
    const int* __restrict__ flag, int bw, int l){
  __shared__ float a[16];
  __shared__ float red[10];
  int f=*flag;
  int tok = blockIdx.x, tid = threadIdx.x;
  if (tid<16) a[tid] = attn[(size_t)tok*16 + tid];
  __syncthreads();
  float v[2], sum=0.f, sq=0.f;
  size_t wbase = (size_t)l*EE*16;
  #pragma unroll
  for (int p=0;p<2;++p){
    int e = tid + p*256;
    float w[16];
    #pragma unroll
    for (int q4=0;q4<4;++q4){
      float4 wv = ldg4(Wc,f, wbase + (size_t)e*16 + q4*4);
      w[q4*4+0]=wv.x; w[q4*4+1]=wv.y; w[q4*4+2]=wv.z; w[q4*4+3]=wv.w;
    }
    float acc = ldh(ho,hw,f,bw,(size_t)tok*EE + e);
    #pragma unroll
    for (int q=0;q<16;++q) acc = fmaf(a[q], w[q], acc);
    v[p]=acc; sum+=acc; sq=fmaf(acc,acc,sq);
  }
  #pragma unroll
  for (int off=32; off; off>>=1){ sum += __shfl_down(sum,off); sq += __shfl_down(sq,off); }
  int wid = tid>>6;
  if ((tid&63)==0){ red[wid*2]=sum; red[wid*2+1]=sq; }
  __syncthreads();
  if (tid==0){
    float s=0.f, s2=0.f;
    #pragma unroll
    for (int w2=0; w2<4; ++w2){ s+=red[w2*2]; s2+=red[w2*2+1]; }
    float m = s*(1.f/512.f);
    float var = s2*(1.f/512.f) - m*m;
    red[8]=m; red[9]=rsqrtf(var+1e-5f);
  }
  __syncthreads();
  float m=red[8], rs=red[9];
  #pragma unroll
  for (int p=0;p<2;++p){
    int e = tid + p*256;
    float gg = ldg(g,f,(size_t)l*EE+e), bv = ldg(bb,f,(size_t)l*EE+e);
    sth(ho,hw,f,bw,(size_t)tok*EE + e, fmaf((v[p]-m)*rs, gg, bv));
  }
}

// FFN + residual + LayerNorm. 16 tokens per block, full E=512 per block.
__global__ __launch_bounds__(256) void ffn_ln_k(void* ho, float* hw,
    const void* __restrict__ thf, const void* __restrict__ W1,
    const void* __restrict__ W2, const void* __restrict__ g,
    const void* __restrict__ bb, const int* __restrict__ flag, int bw, int l){
  __shared__ float SM[8832];
  float* w2t  = SM;            // [512][16], float4-swizzled
  float* hid  = SM + 8192;     // [16][20]
  float* w1c  = SM + 8512;     // [16][17]
  float* cth  = SM + 8784;     // [16]
  float* mres = SM + 8800;     // [16][2]
  float* outL = SM;            // overlay [16][516] = 8256 floats (w2t+hid dead)

  int f=*flag;
  int tid = threadIdx.x, tok0 = blockIdx.x*16;
  if (tid<16) cth[tid] = __cosf(ldg(thf,f,(size_t)l*16 + tid));

  int tq = tid>>4;
  float qr[16];
  {
    size_t hb = (size_t)(tok0+tq)*EE;
    #pragma unroll
    for (int q=0;q<16;++q) qr[q] = __cosf(ldh(ho,hw,f,bw, hb+q));
  }
  int tg = tid&7, eg = tid>>3, kkq = tid&15;
  float acc[2][16];
  #pragma unroll
  for (int i=0;i<2;++i)
    #pragma unroll
    for (int j=0;j<16;++j) acc[i][j]=0.f;

  __syncthreads();

  size_t w1base = (size_t)l*FF*16;
  size_t w2base = (size_t)l*EE*FF;
  for (int k0=0; k0<FF; k0+=16){
    if (tid<32){
      int kk = tid>>1, qo = (tid&1)*8;
      size_t bidx = w1base + (size_t)(k0+kk)*16 + qo;
      float4 A = ldg4(W1,f,bidx), Bv = ldg4(W1,f,bidx+4);
      w1c[kk*17+qo+0]=A.x*cth[qo+0];  w1c[kk*17+qo+1]=A.y*cth[qo+1];
      w1c[kk*17+qo+2]=A.z*cth[qo+2];  w1c[kk*17+qo+3]=A.w*cth[qo+3];
      w1c[kk*17+qo+4]=Bv.x*cth[qo+4]; w1c[kk*17+qo+5]=Bv.y*cth[qo+5];
      w1c[kk*17+qo+6]=Bv.z*cth[qo+6]; w1c[kk*17+qo+7]=Bv.w*cth[qo+7];
    }
    #pragma unroll
    for (int r=0;r<2;++r){
      int e = tid + r*256;
      size_t src = w2base + (size_t)e*FF + k0;
      int sw = ((e>>1)&3)*4;
      #pragma unroll
      for (int gq=0;gq<4;++gq){
        float4 wv = ldg4(W2,f,src + gq*4);
        *(float4*)&w2t[e*16 + ((gq*4)^sw)] = wv;
      }
    }
    __syncthreads();
    {
      float s=0.f;
      #pragma unroll
      for (int q=0;q<16;++q) s = fmaf(qr[q], w1c[kkq*17+q], s);
      hid[tq*20 + kkq] = fmaxf(s,0.f);
    }
    __syncthreads();
    #pragma unroll
    for (int kk4=0; kk4<16; kk4+=4){
      float4 h0 = *(const float4*)&hid[tg*20 + kk4];
      float4 h1 = *(const float4*)&hid[(tg+8)*20 + kk4];
      #pragma unroll
      for (int j=0;j<16;++j){
        int e = eg + 32*j;
        float4 wv = *(const float4*)&w2t[e*16 + (kk4 ^ (((e>>1)&3)*4))];
        acc[0][j]=fmaf(h0.x,wv.x,fmaf(h0.y,wv.y,fmaf(h0.z,wv.z,fmaf(h0.w,wv.w,acc[0][j]))));
        acc[1][j]=fmaf(h1.x,wv.x,fmaf(h1.y,wv.y,fmaf(h1.z,wv.z,fmaf(h1.w,wv.w,acc[1][j]))));
      }
    }
    __syncthreads();
  }

  #pragma unroll
  for (int i=0;i<2;++i){
    int tok = tg + 8*i;
    size_t hb = (size_t)(tok0+tok)*EE;
    #pragma unroll
    for (int j=0;j<16;++j){
      int e = eg + 32*j;
      outL[tok*516 + e] = acc[i][j] + ldh(ho,hw,f,bw, hb+e);
    }
  }
  __syncthreads();
  {
    int token = tid>>4, part = tid&15;
    float s=0.f, s2=0.f;
    #pragma unroll 8
    for (int i2=0;i2<32;++i2){
      float vv = outL[token*516 + part + 16*i2];
      s += vv; s2 = fmaf(vv,vv,s2);
    }
    #pragma unroll
    for (int off=8; off; off>>=1){ s += __shfl_down(s,off,16); s2 += __shfl_down(s2,off,16); }
    if (part==0){
      float m = s*(1.f/512.f);
      float var = s2*(1.f/512.f) - m*m;
      mres[token*2]   = m;
      mres[token*2+1] = rsqrtf(var+1e-5f);
    }
  }
  __syncthreads();
  for (int u=tid; u<16*128; u+=256){
    int tok = u>>7, c4 = (u&127)*4;
    float4 vv = *(const float4*)&outL[tok*516 + c4];
    float m = mres[tok*2], rs = mres[tok*2+1];
    float4 gv = ldg4(g,f,(size_t)l*EE + c4);
    float4 bv = ldg4(bb,f,(size_t)l*EE + c4);
    float4 o;
    o.x = fmaf((vv.x-m)*rs, gv.x, bv.x);
    o.y = fmaf((vv.y-m)*rs, gv.y, bv.y);
    o.z = fmaf((vv.z-m)*rs, gv.z, bv.z);
    o.w = fmaf((vv.w-m)*rs, gv.w, bv.w);
    sth4(ho,hw,f,bw,(size_t)(tok0+tok)*EE + c4, o);
  }
}

// only launched when bw==1: if bf16-world, convert fp32 h (ws) -> bf16 d_out
__global__ __launch_bounds__(256) void conv_k(const float* __restrict__ hw,
    u16* __restrict__ out, const int* __restrict__ flag){
  if (*flag) return;   // fp32-world: h already lives in d_out
  size_t i = ((size_t)blockIdx.x*256 + threadIdx.x)*4;
  float4 v = *(const float4*)(hw + i);
  ushort4 o; o.x=f2bf(v.x); o.y=f2bf(v.y); o.z=f2bf(v.z); o.w=f2bf(v.w);
  *(ushort4*)(out + i) = o;
}

extern "C" void kernel_launch(void* const* d_in, const int* in_sizes, int n_in,
                              void* d_out, int out_size, void* d_ws, size_t ws_size,
                              hipStream_t stream) {
  (void)in_sizes; (void)n_in; (void)out_size;
  int*   flag = (int*)d_ws;
  float* attn = (float*)((char*)d_ws + 256);            // 512 KiB
  float* hw   = (float*)((char*)d_ws + (1u<<20));       // 16 MiB (optional)
  int bw = (ws_size >= ((size_t)18<<20)) ? 1 : 0;       // host-constant -> graph-safe

  detect_k<<<1,256,0,stream>>>((const u16*)d_in[0], flag);
  add_pe_k<<<4096,256,0,stream>>>(d_in[0], d_in[1], d_out, hw, flag, bw);
  for (int l=0; l<4; ++l){
    attn_k<<<dim3(64,4),256,0,stream>>>(d_out, hw, d_in[2], attn, flag, bw, l);
    combine_ln_k<<<BB*SS,256,0,stream>>>(d_out, hw, attn, d_in[4],
                                         d_in[7], d_in[8], flag, bw, l);
    ffn_ln_k<<<BB*SS/16,256,0,stream>>>(d_out, hw, d_in[3], d_in[5], d_in[6],
                                        d_in[9], d_in[10], flag, bw, l);
  }
  if (bw) conv_k<<<4096,256,0,stream>>>(hw, (u16*)d_out, flag);
}

// Round 3
// 911.108 us; speedup vs baseline: 2.6310x; 2.6310x over previous
//
#include <hip/hip_runtime.h>
#include <cstdint>
#include <cstddef>

#define BB 8
#define SS 1024
#define EE 512
#define NQB 16
#define FF 2048

typedef unsigned short u16;
typedef __attribute__((ext_vector_type(8))) short short8;
typedef __attribute__((ext_vector_type(4))) float f32x4;

__device__ __forceinline__ float u2f(u16 u){ return __uint_as_float(((unsigned)u)<<16); }
__device__ __forceinline__ u16 f2bf(float x){
  unsigned u = __float_as_uint(x);
  u += 0x7FFF + ((u>>16)&1);   // RNE
  return (u16)(u>>16);
}

// dual-dtype global load helpers. f=1: fp32 data, f=0: bf16 data.
__device__ __forceinline__ float ldg(const void* p,int f,size_t i){
  return f ? ((const float*)p)[i] : u2f(((const u16*)p)[i]);
}
__device__ __forceinline__ float4 ldg4(const void* p,int f,size_t i){ // i multiple of 4
  float4 r;
  if (f){ r = ((const float4*)p)[i>>2]; }
  else { ushort4 v = ((const ushort4*)p)[i>>2];
         r.x=u2f(v.x); r.y=u2f(v.y); r.z=u2f(v.z); r.w=u2f(v.w); }
  return r;
}
// load 8 consecutive elements starting at i (i multiple of 8) as a bf16x8 frag
__device__ __forceinline__ short8 ldfrag8(const void* p,int f,size_t i){
  short8 r;
  if (f){
    float4 A  = ((const float4*)p)[i>>2];
    float4 Bv = ((const float4*)p)[(i>>2)+1];
    r[0]=(short)f2bf(A.x);  r[1]=(short)f2bf(A.y);  r[2]=(short)f2bf(A.z);  r[3]=(short)f2bf(A.w);
    r[4]=(short)f2bf(Bv.x); r[5]=(short)f2bf(Bv.y); r[6]=(short)f2bf(Bv.z); r[7]=(short)f2bf(Bv.w);
  } else {
    r = *(const short8*)((const u16*)p + i);
  }
  return r;
}
// h accessors: f=1 -> fp32 in d_out; f=0 && bw=1 -> fp32 in ws; else bf16 in d_out.
__device__ __forceinline__ float ldh(const void* ho,const float* hw,int f,int bw,size_t i){
  if (f)  return ((const float*)ho)[i];
  if (bw) return hw[i];
  return u2f(((const u16*)ho)[i]);
}
__device__ __forceinline__ void sth(void* ho,float* hw,int f,int bw,size_t i,float v){
  if (f){ ((float*)ho)[i]=v; return; }
  if (bw){ hw[i]=v; return; }
  ((u16*)ho)[i]=f2bf(v);
}
__device__ __forceinline__ void sth4(void* ho,float* hw,int f,int bw,size_t i,float4 v){
  if (f){ ((float4*)ho)[i>>2]=v; return; }
  if (bw){ ((float4*)hw)[i>>2]=v; return; }
  ushort4 o; o.x=f2bf(v.x); o.y=f2bf(v.y); o.z=f2bf(v.z); o.w=f2bf(v.w);
  ((ushort4*)ho)[i>>2]=o;
}

// dtype detector (unchanged from passing round)
__global__ void detect_k(const u16* __restrict__ x, int* __restrict__ flag){
  __shared__ int cnt;
  if (threadIdx.x==0) cnt=0;
  __syncthreads();
  int c=0;
  for (int i=threadIdx.x;i<4096;i+=256){
    u16 v = x[(size_t)i*2];
    int ex = (v>>7)&0xFF;
    c += (ex>=160) ? 1 : 0;
  }
  atomicAdd(&cnt,c);
  __syncthreads();
  if (threadIdx.x==0) *flag = (cnt>64) ? 1 : 0;
}

__global__ __launch_bounds__(256) void add_pe_k(const void* __restrict__ x,
    const void* __restrict__ pe, void* ho, float* hw,
    const int* __restrict__ flag, int bw){
  int f=*flag;
  size_t e = ((size_t)blockIdx.x*256 + threadIdx.x)*4;
  float4 xv = ldg4(x,f,e);
  float4 pv = ldg4(pe,f,e & (size_t)(SS*EE-1));
  float4 o; o.x=xv.x+pv.x; o.y=xv.y+pv.y; o.z=xv.z+pv.z; o.w=xv.w+pv.w;
  sth4(ho,hw,f,bw,e,o);
}

__global__ __launch_bounds__(256) void attn_k(const void* __restrict__ ho,
    const float* __restrict__ hw, const void* __restrict__ theta,
    float* __restrict__ attn, const int* __restrict__ flag, int bw, int l){
  __shared__ float q0[SS], q1[SS];
  int f=*flag;
  int b = blockIdx.x>>3, hd = blockIdx.x&7;
  float c0 = __cosf(ldg(theta,f,(size_t)l*16 + hd*2));
  float c1 = __cosf(ldg(theta,f,(size_t)l*16 + hd*2+1));
  size_t hb = (size_t)b*SS*EE + hd*2;
  for (int j=threadIdx.x; j<SS; j+=256){
    q0[j] = c0*__cosf(ldh(ho,hw,f,bw, hb + (size_t)j*EE));
    q1[j] = c1*__cosf(ldh(ho,hw,f,bw, hb + (size_t)j*EE + 1));
  }
  __syncthreads();
  int r = blockIdx.y*256 + threadIdx.x;
  float a0=q0[r], a1=q1[r], den=0.f, n0=0.f, n1=0.f;
  const float sc = 0.70710678118f;
  for (int j=0;j<SS;++j){
    float u0=q0[j], u1=q1[j];
    float e = __expf((a0*u0 + a1*u1)*sc);
    den += e; n0 = fmaf(e,u0,n0); n1 = fmaf(e,u1,n1);
  }
  float inv = 1.f/den;
  float* ap = attn + ((size_t)(b*SS + r))*NQB + hd*2;
  ap[0]=n0*inv; ap[1]=n1*inv;
}

__global__ __launch_bounds__(256) void combine_ln_k(void* ho, float* hw,
    const float* __restrict__ attn, const void* __restrict__ Wc,
    const void* __restrict__ g, const void* __restrict__ bb,
    const int* __restrict__ flag, int bw, int l){
  __shared__ float a[16];
  __shared__ float red[10];
  int f=*flag;
  int tok = blockIdx.x, tid = threadIdx.x;
  if (tid<16) a[tid] = attn[(size_t)tok*16 + tid];
  __syncthreads();
  float v[2], sum=0.f, sq=0.f;
  size_t wbase = (size_t)l*EE*16;
  #pragma unroll
  for (int p=0;p<2;++p){
    int e = tid + p*256;
    float w[16];
    #pragma unroll
    for (int q4=0;q4<4;++q4){
      float4 wv = ldg4(Wc,f, wbase + (size_t)e*16 + q4*4);
      w[q4*4+0]=wv.x; w[q4*4+1]=wv.y; w[q4*4+2]=wv.z; w[q4*4+3]=wv.w;
    }
    float acc = ldh(ho,hw,f,bw,(size_t)tok*EE + e);
    #pragma unroll
    for (int q=0;q<16;++q) acc = fmaf(a[q], w[q], acc);
    v[p]=acc; sum+=acc; sq=fmaf(acc,acc,sq);
  }
  #pragma unroll
  for (int off=32; off; off>>=1){ sum += __shfl_down(sum,off); sq += __shfl_down(sq,off); }
  int wid = tid>>6;
  if ((tid&63)==0){ red[wid*2]=sum; red[wid*2+1]=sq; }
  __syncthreads();
  if (tid==0){
    float s=0.f, s2=0.f;
    #pragma unroll
    for (int w2=0; w2<4; ++w2){ s+=red[w2*2]; s2+=red[w2*2+1]; }
    float m = s*(1.f/512.f);
    float var = s2*(1.f/512.f) - m*m;
    red[8]=m; red[9]=rsqrtf(var+1e-5f);
  }
  __syncthreads();
  float m=red[8], rs=red[9];
  #pragma unroll
  for (int p=0;p<2;++p){
    int e = tid + p*256;
    float gg = ldg(g,f,(size_t)l*EE+e), bv = ldg(bb,f,(size_t)l*EE+e);
    sth(ho,hw,f,bw,(size_t)tok*EE + e, fmaf((v[p]-m)*rs, gg, bv));
  }
}

// ===== MFMA FFN: 32 tokens x 512 E per block, K=2048 in 64-chunks =====
// GEMM1: Hc[32x64] = relu(Q'[32x16] @ W1[64x16]^T), Q' = cos(theta)*cos(h[:, :16])
// GEMM2: O[32x512] += Hc @ W2tile^T, B-frags straight from global (L2-resident)
// Epilogue: +residual, LayerNorm, write h.
#define HS 88   // Hc row stride (bf16 elements): 64 + 24 pad -> 2-way banks only
__global__ __launch_bounds__(512) void ffn_mfma_k(void* ho, float* hw,
    const void* __restrict__ thf, const void* __restrict__ W1,
    const void* __restrict__ W2, const void* __restrict__ g,
    const void* __restrict__ bb, const int* __restrict__ flag, int bw, int l){
  __shared__ float SM[16576];
  u16*   Hc   = (u16*)SM;        // 2 x [32][HS] bf16 = 11264 B (K-loop only)
  float* outL = SM;              // [32][516] fp32 overlay (epilogue)
  float* mres = SM + 16512;      // [32][2]

  int f = *flag;
  int tid = threadIdx.x;
  int w = tid >> 6, lane = tid & 63;
  int quad = lane >> 4, col = lane & 15;
  int tok0 = blockIdx.x * 32;
  int mtH = w & 1;          // GEMM1: this wave's M-tile
  int kft = w >> 1;         // GEMM1: this wave's kf-tile (0..3)

  // A0 fragment (fixed for whole K loop): A[m=col][k=quad*8+j], zeros for k>=16
  short8 a0 = {0,0,0,0,0,0,0,0};
  if (quad < 2){
    size_t hb = (size_t)(tok0 + mtH*16 + col)*EE + quad*8;
    #pragma unroll
    for (int j=0;j<8;++j){
      int q = quad*8 + j;
      float th = ldg(thf, f, (size_t)l*16 + q);
      a0[j] = (short)f2bf(__cosf(th) * __cosf(ldh(ho,hw,f,bw, hb + j)));
    }
  }

  f32x4 acc[2][4];
  #pragma unroll
  for (int mt=0;mt<2;++mt)
    #pragma unroll
    for (int et=0;et<4;++et)
      acc[mt][et] = (f32x4){0.f,0.f,0.f,0.f};

  size_t w1base = (size_t)l*FF*16;
  size_t w2base = (size_t)l*EE*FF;
  const f32x4 zc = {0.f,0.f,0.f,0.f};

  for (int k0 = 0; k0 < FF; k0 += 64){
    u16* Hb = Hc + ((k0 >> 6) & 1)*(32*HS);
    // --- GEMM1: wave computes tile [mtH][kft] of Hc
    short8 b1 = {0,0,0,0,0,0,0,0};
    if (quad < 2)
      b1 = ldfrag8(W1, f, w1base + (size_t)(k0 + kft*16 + col)*16 + quad*8);
    f32x4 hc = __builtin_amdgcn_mfma_f32_16x16x32_bf16(a0, b1, zc, 0, 0, 0);
    #pragma unroll
    for (int r=0;r<4;++r)
      Hb[(mtH*16 + quad*4 + r)*HS + kft*16 + col] = f2bf(fmaxf(hc[r], 0.f));
    __syncthreads();
    // --- GEMM2: wave covers E cols [w*64, w*64+64)
    #pragma unroll
    for (int s=0;s<2;++s){
      short8 A2[2];
      #pragma unroll
      for (int mt=0;mt<2;++mt)
        A2[mt] = *(const short8*)&Hb[(mt*16 + col)*HS + s*32 + quad*8];
      #pragma unroll
      for (int et=0;et<4;++et){
        short8 b2 = ldfrag8(W2, f,
            w2base + (size_t)(w*64 + et*16 + col)*FF + (k0 + s*32 + quad*8));
        acc[0][et] = __builtin_amdgcn_mfma_f32_16x16x32_bf16(A2[0], b2, acc[0][et], 0,0,0);
        acc[1][et] = __builtin_amdgcn_mfma_f32_16x16x32_bf16(A2[1], b2, acc[1][et], 0,0,0);
      }
    }
  }
  __syncthreads();   // all Hc reads done before outL overlay

  // epilogue: residual add into outL  (C layout: row=quad*4+r, col=lane&15)
  #pragma unroll
  for (int mt=0; mt<2; ++mt){
    #pragma unroll
    for (int r=0;r<4;++r){
      int ltok = mt*16 + quad*4 + r;
      size_t hb = (size_t)(tok0+ltok)*EE;
      #pragma unroll
      for (int et=0;et<4;++et){
        int e = w*64 + et*16 + col;
        outL[ltok*516 + e] = acc[mt][et][r] + ldh(ho,hw,f,bw, hb + e);
      }
    }
  }
  __syncthreads();
  // LayerNorm stats: 16 threads per token, 32 tokens
  {
    int token = tid>>4, part = tid&15;
    float s=0.f, s2=0.f;
    #pragma unroll 8
    for (int i2=0;i2<32;++i2){
      float vv = outL[token*516 + part + 16*i2];
      s += vv; s2 = fmaf(vv,vv,s2);
    }
    #pragma unroll
    for (int off=8; off; off>>=1){ s += __shfl_down(s,off,16); s2 += __shfl_down(s2,off,16); }
    if (part==0){
      float m = s*(1.f/512.f);
      float var = s2*(1.f/512.f) - m*m;
      mres[token*2]   = m;
      mres[token*2+1] = rsqrtf(var+1e-5f);
    }
  }
  __syncthreads();
  for (int u=tid; u<32*128; u+=512){
    int tok = u>>7, c4 = (u&127)*4;
    float4 vv = *(const float4*)&outL[tok*516 + c4];
    float m = mres[tok*2], rs = mres[tok*2+1];
    float4 gv = ldg4(g,f,(size_t)l*EE + c4);
    float4 bv = ldg4(bb,f,(size_t)l*EE + c4);
    float4 o;
    o.x = fmaf((vv.x-m)*rs, gv.x, bv.x);
    o.y = fmaf((vv.y-m)*rs, gv.y, bv.y);
    o.z = fmaf((vv.z-m)*rs, gv.z, bv.z);
    o.w = fmaf((vv.w-m)*rs, gv.w, bv.w);
    sth4(ho,hw,f,bw,(size_t)(tok0+tok)*EE + c4, o);
  }
}

__global__ __launch_bounds__(256) void conv_k(const float* __restrict__ hw,
    u16* __restrict__ out, const int* __restrict__ flag){
  if (*flag) return;
  size_t i = ((size_t)blockIdx.x*256 + threadIdx.x)*4;
  float4 v = *(const float4*)(hw + i);
  ushort4 o; o.x=f2bf(v.x); o.y=f2bf(v.y); o.z=f2bf(v.z); o.w=f2bf(v.w);
  *(ushort4*)(out + i) = o;
}

extern "C" void kernel_launch(void* const* d_in, const int* in_sizes, int n_in,
                              void* d_out, int out_size, void* d_ws, size_t ws_size,
                              hipStream_t stream) {
  (void)in_sizes; (void)n_in; (void)out_size;
  int*   flag = (int*)d_ws;
  float* attn = (float*)((char*)d_ws + 256);
  float* hw   = (float*)((char*)d_ws + (1u<<20));
  int bw = (ws_size >= ((size_t)18<<20)) ? 1 : 0;

  detect_k<<<1,256,0,stream>>>((const u16*)d_in[0], flag);
  add_pe_k<<<4096,256,0,stream>>>(d_in[0], d_in[1], d_out, hw, flag, bw);
  for (int l=0; l<4; ++l){
    attn_k<<<dim3(64,4),256,0,stream>>>(d_out, hw, d_in[2], attn, flag, bw, l);
    combine_ln_k<<<BB*SS,256,0,stream>>>(d_out, hw, attn, d_in[4],
                                         d_in[7], d_in[8], flag, bw, l);
    ffn_mfma_k<<<256,512,0,stream>>>(d_out, hw, d_in[3], d_in[5], d_in[6],
                                     d_in[9], d_in[10], flag, bw, l);
  }
  if (bw) conv_k<<<4096,256,0,stream>>>(hw, (u16*)d_out, flag);
}

// Round 4
// 650.771 us; speedup vs baseline: 3.6836x; 1.4000x over previous
//
#include <hip/hip_runtime.h>
#include <cstdint>
#include <cstddef>

#define BB 8
#define SS 1024
#define EE 512
#define NQB 16
#define FF 2048
#define HS2 1032   // Hc row stride in bf16 elems: 1024 + 8 -> 4-bank row shift

typedef unsigned short u16;
typedef __attribute__((ext_vector_type(8))) short short8;
typedef __attribute__((ext_vector_type(4))) float f32x4;

__device__ __forceinline__ float u2f(u16 u){ return __uint_as_float(((unsigned)u)<<16); }
__device__ __forceinline__ u16 f2bf(float x){
  unsigned u = __float_as_uint(x);
  u += 0x7FFF + ((u>>16)&1);   // RNE
  return (u16)(u>>16);
}

// dual-dtype global load helpers. f=1: fp32 data, f=0: bf16 data.
__device__ __forceinline__ float ldg(const void* p,int f,size_t i){
  return f ? ((const float*)p)[i] : u2f(((const u16*)p)[i]);
}
__device__ __forceinline__ float4 ldg4(const void* p,int f,size_t i){ // i multiple of 4
  float4 r;
  if (f){ r = ((const float4*)p)[i>>2]; }
  else { ushort4 v = ((const ushort4*)p)[i>>2];
         r.x=u2f(v.x); r.y=u2f(v.y); r.z=u2f(v.z); r.w=u2f(v.w); }
  return r;
}
__device__ __forceinline__ short8 ldfrag8(const void* p,int f,size_t i){ // i mult of 8
  short8 r;
  if (f){
    float4 A  = ((const float4*)p)[i>>2];
    float4 Bv = ((const float4*)p)[(i>>2)+1];
    r[0]=(short)f2bf(A.x);  r[1]=(short)f2bf(A.y);  r[2]=(short)f2bf(A.z);  r[3]=(short)f2bf(A.w);
    r[4]=(short)f2bf(Bv.x); r[5]=(short)f2bf(Bv.y); r[6]=(short)f2bf(Bv.z); r[7]=(short)f2bf(Bv.w);
  } else {
    r = *(const short8*)((const u16*)p + i);
  }
  return r;
}
__device__ __forceinline__ float ldh(const void* ho,const float* hw,int f,int bw,size_t i){
  if (f)  return ((const float*)ho)[i];
  if (bw) return hw[i];
  return u2f(((const u16*)ho)[i]);
}
__device__ __forceinline__ void sth(void* ho,float* hw,int f,int bw,size_t i,float v){
  if (f){ ((float*)ho)[i]=v; return; }
  if (bw){ hw[i]=v; return; }
  ((u16*)ho)[i]=f2bf(v);
}
__device__ __forceinline__ void sth4(void* ho,float* hw,int f,int bw,size_t i,float4 v){
  if (f){ ((float4*)ho)[i>>2]=v; return; }
  if (bw){ ((float4*)hw)[i>>2]=v; return; }
  ushort4 o; o.x=f2bf(v.x); o.y=f2bf(v.y); o.z=f2bf(v.z); o.w=f2bf(v.w);
  ((ushort4*)ho)[i>>2]=o;
}

__global__ void detect_k(const u16* __restrict__ x, int* __restrict__ flag){
  __shared__ int cnt;
  if (threadIdx.x==0) cnt=0;
  __syncthreads();
  int c=0;
  for (int i=threadIdx.x;i<4096;i+=256){
    u16 v = x[(size_t)i*2];
    int ex = (v>>7)&0xFF;
    c += (ex>=160) ? 1 : 0;
  }
  atomicAdd(&cnt,c);
  __syncthreads();
  if (threadIdx.x==0) *flag = (cnt>64) ? 1 : 0;
}

// one-shot: W2 fp32 -> bf16, fragment-major: frag(l,te,kb) holds 64 lanes x 8 elems
// elem = W2[l][te*16+col][kb*32+quad*8+j], lane = quad*16+col. Only if fp32-world.
__global__ __launch_bounds__(256) void w2pack_k(const float* __restrict__ W2f,
    u16* __restrict__ out, const int* __restrict__ flag){
  if (!*flag) return;
  int idx = blockIdx.x*256 + threadIdx.x;        // 0 .. 524287
  int lane = idx & 63, kb = (idx>>6)&63, te = (idx>>12)&31, l = idx>>17;
  int quad = lane>>4, col = lane&15;
  size_t src = ((size_t)l*EE + te*16 + col)*FF + kb*32 + quad*8;
  const float4* q = (const float4*)(W2f + src);
  float4 A = q[0], Bv = q[1];
  short8 r;
  r[0]=(short)f2bf(A.x);  r[1]=(short)f2bf(A.y);  r[2]=(short)f2bf(A.z);  r[3]=(short)f2bf(A.w);
  r[4]=(short)f2bf(Bv.x); r[5]=(short)f2bf(Bv.y); r[6]=(short)f2bf(Bv.z); r[7]=(short)f2bf(Bv.w);
  *(short8*)(out + (size_t)idx*8) = r;
}

__global__ __launch_bounds__(256) void add_pe_k(const void* __restrict__ x,
    const void* __restrict__ pe, void* ho, float* hw,
    const int* __restrict__ flag, int bw){
  int f=*flag;
  size_t e = ((size_t)blockIdx.x*256 + threadIdx.x)*4;
  float4 xv = ldg4(x,f,e);
  float4 pv = ldg4(pe,f,e & (size_t)(SS*EE-1));
  float4 o; o.x=xv.x+pv.x; o.y=xv.y+pv.y; o.z=xv.z+pv.z; o.w=xv.w+pv.w;
  sth4(ho,hw,f,bw,e,o);
}

__global__ __launch_bounds__(256) void attn_k(const void* __restrict__ ho,
    const float* __restrict__ hw, const void* __restrict__ theta,
    float* __restrict__ attn, const int* __restrict__ flag, int bw, int l){
  __shared__ float q0[SS], q1[SS];
  int f=*flag;
  int b = blockIdx.x>>3, hd = blockIdx.x&7;
  float c0 = __cosf(ldg(theta,f,(size_t)l*16 + hd*2));
  float c1 = __cosf(ldg(theta,f,(size_t)l*16 + hd*2+1));
  size_t hb = (size_t)b*SS*EE + hd*2;
  for (int j=threadIdx.x; j<SS; j+=256){
    q0[j] = c0*__cosf(ldh(ho,hw,f,bw, hb + (size_t)j*EE));
    q1[j] = c1*__cosf(ldh(ho,hw,f,bw, hb + (size_t)j*EE + 1));
  }
  __syncthreads();
  int r = blockIdx.y*256 + threadIdx.x;
  float a0=q0[r], a1=q1[r], den=0.f, n0=0.f, n1=0.f;
  const float sc = 0.70710678118f;
  for (int j=0;j<SS;++j){
    float u0=q0[j], u1=q1[j];
    float e = __expf((a0*u0 + a1*u1)*sc);
    den += e; n0 = fmaf(e,u0,n0); n1 = fmaf(e,u1,n1);
  }
  float inv = 1.f/den;
  float* ap = attn + ((size_t)(b*SS + r))*NQB + hd*2;
  ap[0]=n0*inv; ap[1]=n1*inv;
}

__global__ __launch_bounds__(256) void combine_ln_k(void* ho, float* hw,
    const float* __restrict__ attn, const void* __restrict__ Wc,
    const void* __restrict__ g, const void* __restrict__ bb,
    const int* __restrict__ flag, int bw, int l){
  __shared__ float a[16];
  __shared__ float red[10];
  int f=*flag;
  int tok = blockIdx.x, tid = threadIdx.x;
  if (tid<16) a[tid] = attn[(size_t)tok*16 + tid];
  __syncthreads();
  float v[2], sum=0.f, sq=0.f;
  size_t wbase = (size_t)l*EE*16;
  #pragma unroll
  for (int p=0;p<2;++p){
    int e = tid + p*256;
    float w[16];
    #pragma unroll
    for (int q4=0;q4<4;++q4){
      float4 wv = ldg4(Wc,f, wbase + (size_t)e*16 + q4*4);
      w[q4*4+0]=wv.x; w[q4*4+1]=wv.y; w[q4*4+2]=wv.z; w[q4*4+3]=wv.w;
    }
    float acc = ldh(ho,hw,f,bw,(size_t)tok*EE + e);
    #pragma unroll
    for (int q=0;q<16;++q) acc = fmaf(a[q], w[q], acc);
    v[p]=acc; sum+=acc; sq=fmaf(acc,acc,sq);
  }
  #pragma unroll
  for (int off=32; off; off>>=1){ sum += __shfl_down(sum,off); sq += __shfl_down(sq,off); }
  int wid = tid>>6;
  if ((tid&63)==0){ red[wid*2]=sum; red[wid*2+1]=sq; }
  __syncthreads();
  if (tid==0){
    float s=0.f, s2=0.f;
    #pragma unroll
    for (int w2=0; w2<4; ++w2){ s+=red[w2*2]; s2+=red[w2*2+1]; }
    float m = s*(1.f/512.f);
    float var = s2*(1.f/512.f) - m*m;
    red[8]=m; red[9]=rsqrtf(var+1e-5f);
  }
  __syncthreads();
  float m=red[8], rs=red[9];
  #pragma unroll
  for (int p=0;p<2;++p){
    int e = tid + p*256;
    float gg = ldg(g,f,(size_t)l*EE+e), bv = ldg(bb,f,(size_t)l*EE+e);
    sth(ho,hw,f,bw,(size_t)tok*EE + e, fmaf((v[p]-m)*rs, gg, bv));
  }
}

// ---- phase-B B-fragment providers ----
struct BPk {           // packed bf16, fully coalesced (1 KB/wave/inst)
  const u16* p;        // frag(l, w*4, kbBase) + lane*8
  __device__ __forceinline__ short8 ld(int et,int it) const {
    return *(const short8*)(p + ((size_t)et*64 + it)*512);
  }
};
struct BNat {          // native bf16 W2 [e][k]
  const u16* p;        // W2 + l ofs + (w*64+col)*FF + h0 + quad*8
  __device__ __forceinline__ short8 ld(int et,int it) const {
    return *(const short8*)(p + (size_t)et*16*FF + it*32);
  }
};
struct BF32 {          // fp32 W2 fallback
  const float* p;
  __device__ __forceinline__ short8 ld(int et,int it) const {
    const float4* q = (const float4*)(p + (size_t)et*16*FF + it*32);
    float4 A=q[0], Bv=q[1];
    short8 r;
    r[0]=(short)f2bf(A.x);  r[1]=(short)f2bf(A.y);  r[2]=(short)f2bf(A.z);  r[3]=(short)f2bf(A.w);
    r[4]=(short)f2bf(Bv.x); r[5]=(short)f2bf(Bv.y); r[6]=(short)f2bf(Bv.z); r[7]=(short)f2bf(Bv.w);
    return r;
  }
};

// barrier-free GEMM2 over one K-half (32 steps of k=32), prefetch distance 2
template<class BL>
__device__ __forceinline__ void phaseB_run(const BL& B, const u16* H0, const u16* H1,
                                           f32x4 (&acc)[2][4]){
  short8 Aa[2], Ab[2], Ba[4], Bb[4];
  Aa[0]=*(const short8*)(H0);    Aa[1]=*(const short8*)(H1);
  Ab[0]=*(const short8*)(H0+32); Ab[1]=*(const short8*)(H1+32);
  #pragma unroll
  for (int et=0;et<4;++et){ Ba[et]=B.ld(et,0); Bb[et]=B.ld(et,1); }
  for (int it=0; it<32; it+=2){
    int p0=(it+2)&31, p1=(it+3)&31;     // wraps harmlessly on last iter
    short8 An0[2], Bn0[4], An1[2], Bn1[4];
    An0[0]=*(const short8*)(H0+p0*32); An0[1]=*(const short8*)(H1+p0*32);
    #pragma unroll
    for (int et=0;et<4;++et) Bn0[et]=B.ld(et,p0);
    #pragma unroll
    for (int et=0;et<4;++et){
      acc[0][et]=__builtin_amdgcn_mfma_f32_16x16x32_bf16(Aa[0],Ba[et],acc[0][et],0,0,0);
      acc[1][et]=__builtin_amdgcn_mfma_f32_16x16x32_bf16(Aa[1],Ba[et],acc[1][et],0,0,0);
    }
    An1[0]=*(const short8*)(H0+p1*32); An1[1]=*(const short8*)(H1+p1*32);
    #pragma unroll
    for (int et=0;et<4;++et) Bn1[et]=B.ld(et,p1);
    #pragma unroll
    for (int et=0;et<4;++et){
      acc[0][et]=__builtin_amdgcn_mfma_f32_16x16x32_bf16(Ab[0],Bb[et],acc[0][et],0,0,0);
      acc[1][et]=__builtin_amdgcn_mfma_f32_16x16x32_bf16(Ab[1],Bb[et],acc[1][et],0,0,0);
    }
    Aa[0]=An0[0]; Aa[1]=An0[1]; Ab[0]=An1[0]; Ab[1]=An1[1];
    #pragma unroll
    for (int et=0;et<4;++et){ Ba[et]=Bn0[et]; Bb[et]=Bn1[et]; }
  }
}

// FFN v2: 32 tokens x 512 E per block, K in 2 halves of 1024.
// Phase A: Hc[32][1024] bf16 in LDS (16 MFMA/wave). Phase B: barrier-free GEMM2.
__global__ __launch_bounds__(512) void ffn_v2_k(void* ho, float* hw,
    const void* __restrict__ thf, const void* __restrict__ W1,
    const void* __restrict__ W2, const u16* __restrict__ W2p,
    const void* __restrict__ g, const void* __restrict__ bb,
    const int* __restrict__ flag, int bw, int cv, int l){
  __shared__ float SM[16576];
  u16*   Hc   = (u16*)SM;        // [32][HS2] bf16 = 66,048 B
  float* outL = SM;              // [32][516] fp32 overlay (epilogue)
  float* mres = SM + 16512;

  int f = *flag;
  int tid = threadIdx.x, w = tid>>6, lane = tid&63;
  int quad = lane>>4, col = lane&15;
  int tok0 = blockIdx.x*32, mt = w&1;
  int ntBase = (w>>1)*16;

  // fixed A fragment for GEMM1: cos(theta_q)*cos(h_q), K padded 16->32 with 0
  short8 a0 = {0,0,0,0,0,0,0,0};
  if (quad < 2){
    size_t hb = (size_t)(tok0 + mt*16 + col)*EE + quad*8;
    #pragma unroll
    for (int j=0;j<8;++j){
      int q = quad*8 + j;
      float th = ldg(thf, f, (size_t)l*16 + q);
      a0[j] = (short)f2bf(__cosf(th) * __cosf(ldh(ho,hw,f,bw, hb + j)));
    }
  }

  f32x4 acc[2][4];
  #pragma unroll
  for (int i=0;i<2;++i)
    #pragma unroll
    for (int j=0;j<4;++j) acc[i][j] = (f32x4){0.f,0.f,0.f,0.f};

  size_t w1base = (size_t)l*FF*16;
  size_t w2base = (size_t)l*EE*FF;
  const f32x4 zc = {0.f,0.f,0.f,0.f};

  for (int half=0; half<2; ++half){
    int h0 = half*1024;
    // ---- Phase A: this wave computes 16 tiles of Hc
    #pragma unroll 4
    for (int t=0;t<16;++t){
      int nt = ntBase + t;
      short8 b1 = {0,0,0,0,0,0,0,0};
      if (quad < 2)
        b1 = ldfrag8(W1, f, w1base + (size_t)(h0 + nt*16 + col)*16 + quad*8);
      f32x4 hc = __builtin_amdgcn_mfma_f32_16x16x32_bf16(a0, b1, zc, 0, 0, 0);
      #pragma unroll
      for (int r=0;r<4;++r)
        Hc[(mt*16 + quad*4 + r)*HS2 + nt*16 + col] = f2bf(fmaxf(hc[r], 0.f));
    }
    __syncthreads();
    // ---- Phase B: O[32 x this wave's 64 E-cols] += Hc-half @ W2-half^T
    const u16* H0 = Hc + col*HS2 + quad*8;
    const u16* H1 = H0 + 16*HS2;
    if (f && cv){
      BPk Bp{ W2p + (((size_t)l*32 + w*4)*64 + (h0>>5))*512 + lane*8 };
      phaseB_run(Bp, H0, H1, acc);
    } else if (!f){
      BNat Bp{ (const u16*)W2 + w2base + (size_t)(w*64 + col)*FF + h0 + quad*8 };
      phaseB_run(Bp, H0, H1, acc);
    } else {
      BF32 Bp{ (const float*)W2 + w2base + (size_t)(w*64 + col)*FF + h0 + quad*8 };
      phaseB_run(Bp, H0, H1, acc);
    }
    __syncthreads();
  }

  // ---- epilogue: residual + LayerNorm (outL overlays Hc, now dead)
  #pragma unroll
  for (int mti=0; mti<2; ++mti){
    #pragma unroll
    for (int r=0;r<4;++r){
      int ltok = mti*16 + quad*4 + r;
      size_t hb = (size_t)(tok0+ltok)*EE;
      #pragma unroll
      for (int et=0;et<4;++et){
        int e = w*64 + et*16 + col;
        outL[ltok*516 + e] = acc[mti][et][r] + ldh(ho,hw,f,bw, hb + e);
      }
    }
  }
  __syncthreads();
  {
    int token = tid>>4, part = tid&15;
    float s=0.f, s2=0.f;
    #pragma unroll 8
    for (int i2=0;i2<32;++i2){
      float vv = outL[token*516 + part + 16*i2];
      s += vv; s2 = fmaf(vv,vv,s2);
    }
    #pragma unroll
    for (int off=8; off; off>>=1){ s += __shfl_down(s,off,16); s2 += __shfl_down(s2,off,16); }
    if (part==0){
      float m = s*(1.f/512.f);
      float var = s2*(1.f/512.f) - m*m;
      mres[token*2]   = m;
      mres[token*2+1] = rsqrtf(var+1e-5f);
    }
  }
  __syncthreads();
  for (int u=tid; u<32*128; u+=512){
    int tok = u>>7, c4 = (u&127)*4;
    float4 vv = *(const float4*)&outL[tok*516 + c4];
    float m = mres[tok*2], rs = mres[tok*2+1];
    float4 gv = ldg4(g,f,(size_t)l*EE + c4);
    float4 bv = ldg4(bb,f,(size_t)l*EE + c4);
    float4 o;
    o.x = fmaf((vv.x-m)*rs, gv.x, bv.x);
    o.y = fmaf((vv.y-m)*rs, gv.y, bv.y);
    o.z = fmaf((vv.z-m)*rs, gv.z, bv.z);
    o.w = fmaf((vv.w-m)*rs, gv.w, bv.w);
    sth4(ho,hw,f,bw,(size_t)(tok0+tok)*EE + c4, o);
  }
}

__global__ __launch_bounds__(256) void conv_k(const float* __restrict__ hw,
    u16* __restrict__ out, const int* __restrict__ flag){
  if (*flag) return;
  size_t i = ((size_t)blockIdx.x*256 + threadIdx.x)*4;
  float4 v = *(const float4*)(hw + i);
  ushort4 o; o.x=f2bf(v.x); o.y=f2bf(v.y); o.z=f2bf(v.z); o.w=f2bf(v.w);
  *(ushort4*)(out + i) = o;
}

extern "C" void kernel_launch(void* const* d_in, const int* in_sizes, int n_in,
                              void* d_out, int out_size, void* d_ws, size_t ws_size,
                              hipStream_t stream) {
  (void)in_sizes; (void)n_in; (void)out_size;
  int*   flag = (int*)d_ws;
  float* attn = (float*)((char*)d_ws + 256);                 // 512 KiB
  float* hw   = (float*)((char*)d_ws + ((size_t)1<<20));     // 16 MiB (h fp32, bf16-world)
  u16*   w2p  = (u16*)((char*)d_ws + ((size_t)17<<20));      // 8 MiB packed W2 bf16
  int bw = (ws_size >= ((size_t)18<<20)) ? 1 : 0;            // unchanged semantics
  int cv = (ws_size >= ((size_t)26<<20)) ? 1 : 0;

  detect_k<<<1,256,0,stream>>>((const u16*)d_in[0], flag);
  if (cv) w2pack_k<<<2048,256,0,stream>>>((const float*)d_in[6], w2p, flag);
  add_pe_k<<<4096,256,0,stream>>>(d_in[0], d_in[1], d_out, hw, flag, bw);
  for (int l=0; l<4; ++l){
    attn_k<<<dim3(64,4),256,0,stream>>>(d_out, hw, d_in[2], attn, flag, bw, l);
    combine_ln_k<<<BB*SS,256,0,stream>>>(d_out, hw, attn, d_in[4],
                                         d_in[7], d_in[8], flag, bw, l);
    ffn_v2_k<<<256,512,0,stream>>>(d_out, hw, d_in[3], d_in[5], d_in[6], w2p,
                                   d_in[9], d_in[10], flag, bw, cv, l);
  }
  if (bw) conv_k<<<4096,256,0,stream>>>(hw, (u16*)d_out, flag);
}

// Round 5
// 443.571 us; speedup vs baseline: 5.4043x; 1.4671x over previous
//
#include <hip/hip_runtime.h>
#include <cstdint>
#include <cstddef>

#define BB 8
#define SS 1024
#define EE 512
#define NQB 16
#define FF 2048

typedef unsigned short u16;
typedef __attribute__((ext_vector_type(8))) short short8;
typedef __attribute__((ext_vector_type(4))) float f32x4;
typedef unsigned int uint_g __attribute__((address_space(1)));
typedef unsigned int uint_l __attribute__((address_space(3)));

// ---- ws layout (bytes). Proven budget: ws >= 18 MiB (bw held rounds 2-4).
#define FLAG_OFF   0
#define ATTN_OFF   4096                    // 8192*16*4 = 512 KiB
#define QF_OFF     528384                  // 512 KiB
#define W1P_OFF    1052672                 // 256 KiB
#define STATS_OFF  1314816                 // 256 KiB (reused across layers)
#define H_OFF      2097152                 // 16 MiB  (ends exactly at 18 MiB)
#define W2P_OFF    18874368                // 8 MiB, only if ws >= 26 MiB

__device__ __forceinline__ float u2f(u16 u){ return __uint_as_float(((unsigned)u)<<16); }
__device__ __forceinline__ u16 f2bf(float x){
  unsigned u = __float_as_uint(x);
  u += 0x7FFF + ((u>>16)&1);   // RNE
  return (u16)(u>>16);
}
__device__ __forceinline__ float ldg(const void* p,int f,size_t i){
  return f ? ((const float*)p)[i] : u2f(((const u16*)p)[i]);
}
__device__ __forceinline__ float4 ldg4(const void* p,int f,size_t i){ // i mult of 4
  float4 r;
  if (f){ r = ((const float4*)p)[i>>2]; }
  else { ushort4 v = ((const ushort4*)p)[i>>2];
         r.x=u2f(v.x); r.y=u2f(v.y); r.z=u2f(v.z); r.w=u2f(v.w); }
  return r;
}
__device__ __forceinline__ short8 ldfrag8(const void* p,int f,size_t i){ // i mult of 8
  short8 r;
  if (f){
    float4 A  = ((const float4*)p)[i>>2];
    float4 Bv = ((const float4*)p)[(i>>2)+1];
    r[0]=(short)f2bf(A.x);  r[1]=(short)f2bf(A.y);  r[2]=(short)f2bf(A.z);  r[3]=(short)f2bf(A.w);
    r[4]=(short)f2bf(Bv.x); r[5]=(short)f2bf(Bv.y); r[6]=(short)f2bf(Bv.z); r[7]=(short)f2bf(Bv.w);
  } else {
    r = *(const short8*)((const u16*)p + i);
  }
  return r;
}
__device__ __forceinline__ void async16(const void* g, void* l){
  __builtin_amdgcn_global_load_lds((const uint_g*)g, (uint_l*)l, 16, 0, 0);
}
// lazy-LN helper: m, rs from 4 partial (S1,S2) pairs
__device__ __forceinline__ void tok_stats(const float* st, int tok, float& m, float& rs){
  float S1 = 0.f, S2 = 0.f;
  #pragma unroll
  for (int nb=0; nb<4; ++nb){
    float2 p = *(const float2*)&st[((size_t)tok*4+nb)*2];
    S1 += p.x; S2 += p.y;
  }
  m = S1*(1.f/512.f);
  float var = S2*(1.f/512.f) - m*m;
  rs = rsqrtf(var + 1e-5f);
}

__global__ void detect_k(const u16* __restrict__ x, int* __restrict__ flag){
  __shared__ int cnt;
  if (threadIdx.x==0) cnt=0;
  __syncthreads();
  int c=0;
  for (int i=threadIdx.x;i<4096;i+=256){
    u16 v = x[(size_t)i*2];
    int ex = (v>>7)&0xFF;
    c += (ex>=160) ? 1 : 0;
  }
  atomicAdd(&cnt,c);
  __syncthreads();
  if (threadIdx.x==0) *flag = (cnt>64) ? 1 : 0;
}

// pack W1 (cos(theta_ffn) folded) into B-frag-major bf16: 4 layers x 128 nt x 32 lanes x 8
__global__ __launch_bounds__(256) void w1pack_k(const void* __restrict__ W1,
    const void* __restrict__ thf, u16* __restrict__ W1p, const int* __restrict__ flag){
  int f = *flag;
  int idx = blockIdx.x*256 + threadIdx.x;        // 0..16383
  int l = idx>>12, nt = (idx>>5)&127, lane32 = idx&31;
  int quad = lane32>>4, col = lane32&15;
  short8 v = ldfrag8(W1, f, ((size_t)l*FF + nt*16 + col)*16 + quad*8);
  short8 o;
  #pragma unroll
  for (int j=0;j<8;++j){
    float th = ldg(thf, f, (size_t)l*16 + quad*8 + j);
    o[j] = (short)f2bf(__cosf(th) * u2f((u16)v[j]));
  }
  *(short8*)(W1p + (size_t)idx*8) = o;
}

// pack W2 into B-frag-major bf16: frag(l, teg, kb): 64 lanes x 8 elems
__global__ __launch_bounds__(256) void w2pack_k(const void* __restrict__ W2,
    u16* __restrict__ W2p, const int* __restrict__ flag){
  int f = *flag;
  int idx = blockIdx.x*256 + threadIdx.x;        // 0..524287
  int lane = idx&63, kb = (idx>>6)&63, teg = (idx>>12)&31, l = idx>>17;
  int quad = lane>>4, col = lane&15;
  short8 v = ldfrag8(W2, f, ((size_t)l*EE + teg*16 + col)*FF + kb*32 + quad*8);
  *(short8*)(W2p + (size_t)idx*8) = v;
}

__global__ __launch_bounds__(256) void add_pe_k(const void* __restrict__ x,
    const void* __restrict__ pe, float* __restrict__ hw, const int* __restrict__ flag){
  int f = *flag;
  size_t e = ((size_t)blockIdx.x*256 + threadIdx.x)*4;
  float4 xv = ldg4(x,f,e);
  float4 pv = ldg4(pe,f,e & (size_t)(SS*EE-1));
  float4 o; o.x=xv.x+pv.x; o.y=xv.y+pv.y; o.z=xv.z+pv.z; o.w=xv.w+pv.w;
  *(float4*)&hw[e] = o;
}

// attention, 4-way K-split in-block: 1024 threads = 256 rows x 4 key-quarters
__global__ __launch_bounds__(1024) void attn3_k(const float* __restrict__ hw,
    const void* __restrict__ theta, float* __restrict__ attn,
    const float* __restrict__ st, const void* __restrict__ g2,
    const void* __restrict__ b2, const int* __restrict__ flag, int lazy, int l){
  __shared__ float q0[SS], q1[SS];
  __shared__ float part[SS*3];    // 256 rows x 4 kz x 3
  int f = *flag;
  int b = blockIdx.x>>3, hd = blockIdx.x&7;
  int tid = threadIdx.x;
  float c0 = __cosf(ldg(theta,f,(size_t)l*16 + hd*2));
  float c1 = __cosf(ldg(theta,f,(size_t)l*16 + hd*2+1));
  float ga0=1.f, gb0=0.f, ga1=1.f, gb1=0.f;
  if (lazy){
    size_t gb = (size_t)(l-1)*EE + hd*2;
    ga0 = ldg(g2,f,gb);   gb0 = ldg(b2,f,(size_t)(l-1)*EE + hd*2);
    ga1 = ldg(g2,f,gb+1); gb1 = ldg(b2,f,(size_t)(l-1)*EE + hd*2+1);
  }
  size_t hb = (size_t)b*SS*EE + hd*2;
  {  // stage all 1024 keys (one row per thread)
    int j = tid;
    float v0 = hw[hb + (size_t)j*EE];
    float v1 = hw[hb + (size_t)j*EE + 1];
    if (lazy){
      float m, rs; tok_stats(st, b*SS + j, m, rs);
      v0 = fmaf((v0-m)*rs, ga0, gb0);
      v1 = fmaf((v1-m)*rs, ga1, gb1);
    }
    q0[j] = c0*__cosf(v0);
    q1[j] = c1*__cosf(v1);
  }
  __syncthreads();
  int rloc = tid & 255, kz = tid >> 8;
  int r = blockIdx.y*256 + rloc;
  const float sc = 0.70710678118f;
  float a0 = q0[r]*sc, a1 = q1[r]*sc;
  float den=0.f, n0=0.f, n1=0.f;
  int j0 = kz*256;
  for (int j=j0; j<j0+256; ++j){
    float u0=q0[j], u1=q1[j];
    float e = __expf(fmaf(a1,u1, a0*u0));
    den += e; n0 = fmaf(e,u0,n0); n1 = fmaf(e,u1,n1);
  }
  part[(rloc*4+kz)*3+0]=den; part[(rloc*4+kz)*3+1]=n0; part[(rloc*4+kz)*3+2]=n1;
  __syncthreads();
  if (tid < 256){
    int rr = blockIdx.y*256 + tid;
    float d=0.f, s0=0.f, s1=0.f;
    #pragma unroll
    for (int k=0;k<4;++k){
      d  += part[(tid*4+k)*3+0];
      s0 += part[(tid*4+k)*3+1];
      s1 += part[(tid*4+k)*3+2];
    }
    float inv = 1.f/d;
    float* ap = attn + ((size_t)(b*SS + rr))*NQB + hd*2;
    ap[0]=s0*inv; ap[1]=s1*inv;
  }
}

// combine + eager LN1 + qfeat emit. 32 tokens/block, Wc columns in registers.
__global__ __launch_bounds__(256) void combine2_k(float* __restrict__ hw,
    const float* __restrict__ attn, const void* __restrict__ Wc,
    const void* __restrict__ g1v, const void* __restrict__ b1v,
    const void* __restrict__ g2v, const void* __restrict__ b2v,
    const float* __restrict__ st, float* __restrict__ qf,
    const int* __restrict__ flag, int lazy, int l){
  __shared__ float AFR[32*16];
  __shared__ float MS[32], RS[32];
  __shared__ float outC[32*520];
  int f = *flag;
  int tid = threadIdx.x, tok0 = blockIdx.x*32;
  for (int u=tid; u<512; u+=256)
    AFR[u] = attn[(size_t)(tok0 + (u>>4))*16 + (u&15)];
  if (lazy && tid<32){
    float m, rs; tok_stats(st, tok0+tid, m, rs);
    MS[tid]=m; RS[tid]=rs;
  }
  __syncthreads();
  int e0 = tid*2;
  float wc0[16], wc1[16];
  size_t wb = (size_t)l*EE*16;
  #pragma unroll
  for (int q4=0;q4<4;++q4){
    float4 a = ldg4(Wc,f, wb + (size_t)e0*16     + q4*4);
    float4 b = ldg4(Wc,f, wb + (size_t)(e0+1)*16 + q4*4);
    wc0[q4*4+0]=a.x; wc0[q4*4+1]=a.y; wc0[q4*4+2]=a.z; wc0[q4*4+3]=a.w;
    wc1[q4*4+0]=b.x; wc1[q4*4+1]=b.y; wc1[q4*4+2]=b.z; wc1[q4*4+3]=b.w;
  }
  float gl0=1.f,bl0=0.f,gl1=1.f,bl1=0.f;
  if (lazy){
    size_t gb = (size_t)(l-1)*EE;
    gl0 = ldg(g2v,f,gb+e0);   bl0 = ldg(b2v,f,gb+e0);
    gl1 = ldg(g2v,f,gb+e0+1); bl1 = ldg(b2v,f,gb+e0+1);
  }
  for (int t=0; t<32; ++t){
    float2 hr = *(const float2*)&hw[(size_t)(tok0+t)*EE + e0];
    float v0 = hr.x, v1 = hr.y;
    if (lazy){
      float m = MS[t], rs = RS[t];
      v0 = fmaf((v0-m)*rs, gl0, bl0);
      v1 = fmaf((v1-m)*rs, gl1, bl1);
    }
    float s0 = v0, s1 = v1;
    #pragma unroll
    for (int q4=0;q4<4;++q4){
      float4 av = *(const float4*)&AFR[t*16 + q4*4];
      s0 = fmaf(av.x, wc0[q4*4+0], fmaf(av.y, wc0[q4*4+1], fmaf(av.z, wc0[q4*4+2], fmaf(av.w, wc0[q4*4+3], s0))));
      s1 = fmaf(av.x, wc1[q4*4+0], fmaf(av.y, wc1[q4*4+1], fmaf(av.z, wc1[q4*4+2], fmaf(av.w, wc1[q4*4+3], s1))));
    }
    outC[t*520 + e0] = s0; outC[t*520 + e0 + 1] = s1;
  }
  __syncthreads();
  {  // eager LN1: 8 threads per token
    int token = tid>>3, prt = tid&7;
    float s=0.f, s2=0.f;
    #pragma unroll 8
    for (int i2=0;i2<64;++i2){
      float vv = outC[token*520 + prt + 8*i2];
      s += vv; s2 = fmaf(vv,vv,s2);
    }
    #pragma unroll
    for (int off=4; off; off>>=1){ s += __shfl_down(s,off,8); s2 += __shfl_down(s2,off,8); }
    if (prt==0){
      float m = s*(1.f/512.f);
      float var = s2*(1.f/512.f) - m*m;
      MS[token] = m; RS[token] = rsqrtf(var+1e-5f);
    }
  }
  __syncthreads();
  for (int u=tid; u<32*128; u+=256){
    int tok = u>>7, c4 = (u&127)*4;
    float4 vv = *(const float4*)&outC[tok*520 + c4];
    float m = MS[tok], rs = RS[tok];
    float4 gv = ldg4(g1v,f,(size_t)l*EE + c4);
    float4 bv = ldg4(b1v,f,(size_t)l*EE + c4);
    float4 o;
    o.x = fmaf((vv.x-m)*rs, gv.x, bv.x);
    o.y = fmaf((vv.y-m)*rs, gv.y, bv.y);
    o.z = fmaf((vv.z-m)*rs, gv.z, bv.z);
    o.w = fmaf((vv.w-m)*rs, gv.w, bv.w);
    *(float4*)&hw[(size_t)(tok0+tok)*EE + c4] = o;
    if (c4 < 16){
      float4 qo;
      qo.x=__cosf(o.x); qo.y=__cosf(o.y); qo.z=__cosf(o.z); qo.w=__cosf(o.w);
      *(float4*)&qf[(size_t)(tok0+tok)*16 + c4] = qo;
    }
  }
}

// ===== FFN v3: m97-style. BM=64 tok, BN=128 E, BK=64. grid (128,4), 256 thr.
// GEMM1 from qfeat (cos theta folded in W1p); Hc frag-major in LDS; W2 frags
// async global_load_lds (cv) or reg+ds_write fallback. Lazy LN: writes pre2
// + per-(token,nb) partial sums. No g/b applied here.
__global__ __launch_bounds__(256) void ffn3_k(float* __restrict__ hw,
    const float* __restrict__ qf, const u16* __restrict__ W1p,
    const void* __restrict__ W2, const u16* __restrict__ W2p,
    float* __restrict__ st, const int* __restrict__ flag, int cv, int l){
  __shared__ float SMF[8704];
  u16* HtA = (u16*)SMF;            // 8 slots (mt*2+s) x 512 u16 = 8 KiB
  u16* W2t = (u16*)SMF + 4096;     // 16 slots (te*2+s) x 512 u16 = 16 KiB
  float* outL = SMF;               // overlay [64][132]

  int f = *flag;
  int tid = threadIdx.x, w = tid>>6, lane = tid&63;
  int quad = lane>>4, col = lane&15;
  int mb = blockIdx.x, nb = blockIdx.y;
  int tok0 = mb*64;
  int wm = w&1, wn = w>>1;

  // a0 frags (4 token-groups) from qfeat
  short8 a0[4];
  #pragma unroll
  for (int mt=0; mt<4; ++mt){
    short8 z = {0,0,0,0,0,0,0,0};
    if (quad < 2){
      const float* qp = qf + (size_t)(tok0 + mt*16 + col)*16 + quad*8;
      float4 A = *(const float4*)qp, B = *(const float4*)(qp+4);
      z[0]=(short)f2bf(A.x); z[1]=(short)f2bf(A.y); z[2]=(short)f2bf(A.z); z[3]=(short)f2bf(A.w);
      z[4]=(short)f2bf(B.x); z[5]=(short)f2bf(B.y); z[6]=(short)f2bf(B.z); z[7]=(short)f2bf(B.w);
    }
    a0[mt] = z;
  }

  f32x4 acc[2][4];
  #pragma unroll
  for (int i=0;i<2;++i)
    #pragma unroll
    for (int j=0;j<4;++j) acc[i][j] = (f32x4){0.f,0.f,0.f,0.f};
  const f32x4 zc = {0.f,0.f,0.f,0.f};
  size_t w2base = (size_t)l*EE*FF;

  for (int k0=0; k0<FF; k0+=64){
    // stage W2 frags (4 slots per wave)
    if (cv){
      #pragma unroll
      for (int fi=0; fi<4; ++fi){
        int slot = w*4+fi, te = slot>>1, s = slot&1;
        int kb = (k0>>5) + s;
        const u16* gp = W2p + (((size_t)l*32 + nb*8 + te)*64 + kb)*512 + lane*8;
        async16(gp, &W2t[slot*512]);
      }
    } else {
      #pragma unroll
      for (int fi=0; fi<4; ++fi){
        int slot = w*4+fi, te = slot>>1, s = slot&1;
        short8 v = ldfrag8(W2, f, w2base + (size_t)(nb*128 + te*16 + col)*FF + k0 + s*32 + quad*8);
        *(short8*)&W2t[slot*512 + lane*8] = v;
      }
    }
    // GEMM1: wave w owns k16-column (k0>>4)+w for all 4 token groups
    short8 b1 = {0,0,0,0,0,0,0,0};
    if (quad < 2)
      b1 = *(const short8*)(W1p + (((size_t)l*128 + (k0>>4) + w)*32 + quad*16 + col)*8);
    int s1w = w>>1, koff = (w&1)*16;
    int lane2 = ((koff + col)>>3)*16 + quad*4;
    int jj = col&7;
    #pragma unroll
    for (int mt=0; mt<4; ++mt){
      f32x4 hc = __builtin_amdgcn_mfma_f32_16x16x32_bf16(a0[mt], b1, zc, 0,0,0);
      #pragma unroll
      for (int r=0;r<4;++r)
        HtA[(mt*2+s1w)*512 + (lane2+r)*8 + jj] = f2bf(fmaxf(hc[r], 0.f));
    }
    __syncthreads();
    // GEMM2
    #pragma unroll
    for (int s=0;s<2;++s){
      short8 A2[2], B2[4];
      A2[0] = *(const short8*)&HtA[((wm*2+0)*2+s)*512 + lane*8];
      A2[1] = *(const short8*)&HtA[((wm*2+1)*2+s)*512 + lane*8];
      #pragma unroll
      for (int et=0;et<4;++et)
        B2[et] = *(const short8*)&W2t[((wn*4+et)*2+s)*512 + lane*8];
      #pragma unroll
      for (int et=0;et<4;++et){
        acc[0][et] = __builtin_amdgcn_mfma_f32_16x16x32_bf16(A2[0], B2[et], acc[0][et], 0,0,0);
        acc[1][et] = __builtin_amdgcn_mfma_f32_16x16x32_bf16(A2[1], B2[et], acc[1][et], 0,0,0);
      }
    }
    __syncthreads();
  }

  // epilogue: pre2 = acc + residual into outL (overlay; K-loop LDS dead)
  #pragma unroll
  for (int mt2=0; mt2<2; ++mt2){
    #pragma unroll
    for (int r=0;r<4;++r){
      int ltok = wm*32 + mt2*16 + quad*4 + r;
      size_t hb = (size_t)(tok0+ltok)*EE + nb*128;
      #pragma unroll
      for (int et=0;et<4;++et){
        int eloc = wn*64 + et*16 + col;
        outL[ltok*132 + eloc] = acc[mt2][et][r] + hw[hb + eloc];
      }
    }
  }
  __syncthreads();
  {  // partial LN stats: 4 threads per token
    int token = tid>>2, prt = tid&3;
    float s=0.f, s2=0.f;
    #pragma unroll 8
    for (int i2=0;i2<32;++i2){
      float vv = outL[token*132 + prt + 4*i2];
      s += vv; s2 = fmaf(vv,vv,s2);
    }
    s += __shfl_down(s,2,4); s2 += __shfl_down(s2,2,4);
    s += __shfl_down(s,1,4); s2 += __shfl_down(s2,1,4);
    if (prt==0){
      float2 o; o.x = s; o.y = s2;
      *(float2*)&st[((size_t)(tok0+token)*4 + nb)*2] = o;
    }
  }
  // write pre2
  for (int u=tid; u<64*32; u+=256){
    int tok = u>>5, c4 = (u&31)*4;
    float4 vv = *(const float4*)&outL[tok*132 + c4];
    *(float4*)&hw[(size_t)(tok0+tok)*EE + nb*128 + c4] = vv;
  }
}

// final: apply lazy LN of layer 3 and emit output (bf16 if f==0, fp32 if f==1)
__global__ __launch_bounds__(256) void conv2_k(const float* __restrict__ hw,
    const float* __restrict__ st, const void* __restrict__ g2v,
    const void* __restrict__ b2v, void* __restrict__ out,
    const int* __restrict__ flag){
  int f = *flag;
  size_t i = (size_t)blockIdx.x*256 + threadIdx.x;   // float4 index
  int tok = (int)(i>>7), c4 = ((int)i&127)*4;
  float4 v = *(const float4*)&hw[i*4];
  float m, rs; tok_stats(st, tok, m, rs);
  float4 gv = ldg4(g2v,f,(size_t)3*EE + c4);
  float4 bv = ldg4(b2v,f,(size_t)3*EE + c4);
  float4 o;
  o.x = fmaf((v.x-m)*rs, gv.x, bv.x);
  o.y = fmaf((v.y-m)*rs, gv.y, bv.y);
  o.z = fmaf((v.z-m)*rs, gv.z, bv.z);
  o.w = fmaf((v.w-m)*rs, gv.w, bv.w);
  if (f){
    *(float4*)((float*)out + i*4) = o;
  } else {
    ushort4 ob; ob.x=f2bf(o.x); ob.y=f2bf(o.y); ob.z=f2bf(o.z); ob.w=f2bf(o.w);
    *(ushort4*)((u16*)out + i*4) = ob;
  }
}

extern "C" void kernel_launch(void* const* d_in, const int* in_sizes, int n_in,
                              void* d_out, int out_size, void* d_ws, size_t ws_size,
                              hipStream_t stream) {
  (void)in_sizes; (void)n_in; (void)out_size;
  char* ws = (char*)d_ws;
  int*   flag = (int*)(ws + FLAG_OFF);
  float* attn = (float*)(ws + ATTN_OFF);
  float* qf   = (float*)(ws + QF_OFF);
  u16*   w1p  = (u16*)(ws + W1P_OFF);
  float* st   = (float*)(ws + STATS_OFF);
  float* hw   = (float*)(ws + H_OFF);
  u16*   w2p  = (u16*)(ws + W2P_OFF);
  int cv = (ws_size >= (size_t)W2P_OFF + ((size_t)8<<20)) ? 1 : 0;

  detect_k<<<1,256,0,stream>>>((const u16*)d_in[0], flag);
  w1pack_k<<<64,256,0,stream>>>(d_in[5], d_in[3], w1p, flag);
  if (cv) w2pack_k<<<2048,256,0,stream>>>(d_in[6], w2p, flag);
  add_pe_k<<<4096,256,0,stream>>>(d_in[0], d_in[1], hw, flag);
  for (int l=0; l<4; ++l){
    int lazy = (l>0) ? 1 : 0;
    attn3_k<<<dim3(64,4),1024,0,stream>>>(hw, d_in[2], attn, st,
                                          d_in[9], d_in[10], flag, lazy, l);
    combine2_k<<<256,256,0,stream>>>(hw, attn, d_in[4], d_in[7], d_in[8],
                                     d_in[9], d_in[10], st, qf, flag, lazy, l);
    ffn3_k<<<dim3(128,4),256,0,stream>>>(hw, qf, w1p, d_in[6], w2p,
                                         st, flag, cv, l);
  }
  conv2_k<<<4096,256,0,stream>>>(hw, st, d_in[9], d_in[10], d_out, flag);
}